// Round 2
// baseline (26371.793 us; speedup 1.0000x reference)
//
#include <hip/hip_runtime.h>

#define BB    64
#define TDEC  128
#define TENC  256
#define DIN   256
#define DENC  512
#define HHH   512
#define NG    1536      // 3H
#define KTOT  1280      // DIN + DENC(ctx) + H
#define LDA   65        // padded LDS stride

// ws float offsets (total ~148544 floats = 594 KB)
#define OFF_BAR   0
#define OFF_U     64
#define OFF_ECTX  (OFF_U + 1024)
#define OFF_H     (OFF_ECTX + BB*TENC)
#define OFF_HT    (OFF_H    + BB*HHH)
#define OFF_CTXT  (OFF_HT   + BB*HHH)
#define OFF_RHT   (OFF_CTXT + BB*HHH)

// ---------------- precompute kernels ----------------

// u[e] = sum_o att_w1[e,o] * att_w2[o],  e in [0,1024)
__global__ void k_u(const float* __restrict__ w1, const float* __restrict__ w2,
                    float* __restrict__ u) {
    int e = blockIdx.x;
    int lane = threadIdx.x;           // 64 threads
    float p = 0.f;
    #pragma unroll
    for (int k = lane; k < DENC; k += 64) p += w1[e*DENC + k] * w2[k];
    #pragma unroll
    for (int off = 32; off; off >>= 1) p += __shfl_down(p, off, 64);
    if (lane == 0) u[e] = p;
}

// ectx[r] = dot(C[r,:], u[512:]),  r in [0, B*TENC)
__global__ void k_ectx(const float* __restrict__ C, const float* __restrict__ u,
                       float* __restrict__ ectx) {
    int r = blockIdx.x*4 + (threadIdx.x >> 6);
    int lane = threadIdx.x & 63;
    const float* row = C + (size_t)r*DENC;
    const float* vc  = u + HHH;
    float p = 0.f;
    #pragma unroll
    for (int k = 0; k < DENC/64; ++k) p += row[lane + k*64] * vc[lane + k*64];
    #pragma unroll
    for (int off = 32; off; off >>= 1) p += __shfl_down(p, off, 64);
    if (lane == 0) ectx[r] = p;
}

// ---------------- main persistent kernel ----------------

__device__ __forceinline__ float wave_sum(float v) {
    #pragma unroll
    for (int off = 32; off; off >>= 1) v += __shfl_down(v, off, 64);
    return v;
}
__device__ __forceinline__ float wave_max(float v) {
    #pragma unroll
    for (int off = 32; off; off >>= 1) v = fmaxf(v, __shfl_down(v, off, 64));
    return v;
}

// sense-reversing grid barrier: bar[0]=count, bar[1]=generation
__device__ __forceinline__ void gbar(unsigned* bar) {
    __syncthreads();
    if (threadIdx.x == 0) {
        __threadfence();
        unsigned g = __hip_atomic_load(bar + 1, __ATOMIC_RELAXED, __HIP_MEMORY_SCOPE_AGENT);
        unsigned a = __hip_atomic_fetch_add(bar, 1u, __ATOMIC_ACQ_REL, __HIP_MEMORY_SCOPE_AGENT);
        if (a == 255u) {
            __hip_atomic_store(bar, 0u, __ATOMIC_RELAXED, __HIP_MEMORY_SCOPE_AGENT);
            __hip_atomic_fetch_add(bar + 1, 1u, __ATOMIC_RELEASE, __HIP_MEMORY_SCOPE_AGENT);
        } else {
            while (__hip_atomic_load(bar + 1, __ATOMIC_ACQUIRE, __HIP_MEMORY_SCOPE_AGENT) == g) {
                __builtin_amdgcn_s_sleep(2);
            }
        }
        __threadfence();
    }
    __syncthreads();
}

__launch_bounds__(256, 1)
__global__ void decoder_main(const float* __restrict__ inp,
                             const float* __restrict__ C,
                             const float* __restrict__ Wx,
                             const float* __restrict__ Wh,
                             const float* __restrict__ bias,
                             float* __restrict__ out,
                             float* __restrict__ ws) {
    unsigned* bar = (unsigned*)ws;
    float* u    = ws + OFF_U;
    float* ectx = ws + OFF_ECTX;
    float* h    = ws + OFF_H;      // [m][d]
    float* hT   = ws + OFF_HT;     // [d][m]
    float* ctxT = ws + OFF_CTXT;   // [d][m]
    float* rhT  = ws + OFF_RHT;    // [d][m]

    const int tid = threadIdx.x;
    const int blk = blockIdx.x;

    __shared__ float ldsW[6*KTOT];       // 30 KB : 6 gate columns for this block
    __shared__ float ldsA[64*LDA];       // 16.6 KB : operand chunk [dl][m], stride 65
    __shared__ float att[TENC];
    __shared__ float red[4];
    __shared__ float zh[2][2][64];       // [j3i][0:z,1:h_old][m]

    // stage this block's 6 weight columns once (strided, one-time)
    const int jb = blk*2;
    for (int i = tid; i < 6*KTOT; i += 256) {
        int jj = i / KTOT, dd = i - jj*KTOT;
        int j3i = jj / 3, c = jj - j3i*3;
        int col = jb + j3i + c*HHH;
        ldsW[i] = (dd < DIN+DENC) ? Wx[(size_t)dd*NG + col]
                                  : Wh[(size_t)(dd-(DIN+DENC))*NG + col];
    }

    // zero h, hT
    for (int i = blk*256 + tid; i < BB*HHH; i += 256*256) { h[i] = 0.f; hT[i] = 0.f; }
    gbar(bar);

    const int m    = tid & 63;
    const int g    = tid >> 6;         // wave id
    const int j3i  = g & 1;
    const bool isZR = (g < 2);
    const int j3   = jb + j3i;
    const float* wz = ldsW + (j3i*3 + 0)*KTOT;
    const float* wr = ldsW + (j3i*3 + 1)*KTOT;
    const float* wh = ldsW + (j3i*3 + 2)*KTOT;

    const int b  = blk >> 2;
    const int dc = blk & 3;
    const float* Cb = C + (size_t)b*TENC*DENC;

    for (int t = 0; t < TDEC; ++t) {
        // ===== P1: attention energies + softmax + ctx slice =====
        float hv0 = h[b*HHH + tid];
        float hv1 = h[b*HHH + 256 + tid];
        float wsum = wave_sum(hv0*u[tid] + hv1*u[256 + tid]);
        __syncthreads();
        if ((tid & 63) == 0) red[g] = wsum;
        __syncthreads();
        float sb = red[0]+red[1]+red[2]+red[3];

        float e = fmaxf(sb + ectx[b*TENC + tid], 0.f);
        float wm = wave_max(e);
        __syncthreads();
        if ((tid & 63) == 0) red[g] = wm;
        __syncthreads();
        float mx = fmaxf(fmaxf(red[0],red[1]), fmaxf(red[2],red[3]));
        float ex = __expf(e - mx);
        float wse = wave_sum(ex);
        __syncthreads();
        if ((tid & 63) == 0) red[g] = wse;
        __syncthreads();
        float denom = red[0]+red[1]+red[2]+red[3];
        att[tid] = ex / denom;
        __syncthreads();

        {   // ctx[b, d-slice] = sum_t att[t] * C[b,t,d]  (this block's 128-dim slice)
            const int tq = tid & 31;
            const int th = tid >> 5;
            const int d4 = dc*128 + tq*4;
            const float4* C4 = (const float4*)Cb;
            float4 acc = make_float4(0.f,0.f,0.f,0.f);
            #pragma unroll 8
            for (int q = 0; q < 32; ++q) {
                int tt = th*32 + q;
                float a = att[tt];
                float4 cv = C4[tt*(DENC/4) + (d4 >> 2)];
                acc.x += a*cv.x; acc.y += a*cv.y; acc.z += a*cv.z; acc.w += a*cv.w;
            }
            float4* p4 = (float4*)ldsA;
            p4[th*32 + tq] = acc;
            __syncthreads();
            if (th == 0) {
                float4 s = p4[tq];
                #pragma unroll
                for (int k = 1; k < 8; ++k) {
                    float4 o = p4[k*32 + tq];
                    s.x += o.x; s.y += o.y; s.z += o.z; s.w += o.w;
                }
                ctxT[(d4+0)*BB + b] = s.x;
                ctxT[(d4+1)*BB + b] = s.y;
                ctxT[(d4+2)*BB + b] = s.z;
                ctxT[(d4+3)*BB + b] = s.w;
            }
        }
        gbar(bar);

        // ===== P2: z,r dots (K=1280) on waves 0-1 ; xh dot (K=768) on waves 2-3 =====
        float accA = 0.f, accB = 0.f;
        for (int ck = 0; ck < 20; ++ck) {
            __syncthreads();
            if (ck < 4) {
                // x chunk: coalesced read from inputs, transpose into LDS
                const int base = ck*64;
                for (int i = tid; i < 4096; i += 256) {
                    int mm = i >> 6, dcol = i & 63;
                    ldsA[dcol*LDA + mm] = inp[((size_t)mm*TDEC + t)*DIN + base + dcol];
                }
            } else {
                const float* src = (ck < 12) ? (ctxT + (ck-4)*(64*BB))
                                             : (hT   + (ck-12)*(64*BB));
                for (int i = tid; i < 4096; i += 256) {
                    int dl = i >> 6, mm = i & 63;
                    ldsA[dl*LDA + mm] = src[i];
                }
            }
            __syncthreads();
            const int d0 = ck*64;
            if (isZR) {
                #pragma unroll 8
                for (int dl = 0; dl < 64; ++dl) {
                    float a = ldsA[dl*LDA + m];
                    accA = fmaf(a, wz[d0+dl], accA);
                    accB = fmaf(a, wr[d0+dl], accB);
                }
            } else if (ck < 12) {
                #pragma unroll 8
                for (int dl = 0; dl < 64; ++dl) {
                    accA = fmaf(ldsA[dl*LDA + m], wh[d0+dl], accA);
                }
            }
        }
        if (isZR) {
            float z = 1.f/(1.f + __expf(-(accA + bias[j3])));
            float r = 1.f/(1.f + __expf(-(accB + bias[j3 + HHH])));
            float ho = h[m*HHH + j3];
            rhT[j3*BB + m] = r * ho;     // (r ⊙ h) row for the Wh3 matmul
            zh[j3i][0][m] = z;
            zh[j3i][1][m] = ho;
        }
        gbar(bar);

        // ===== P3: hh = tanh(xh + (r⊙h) @ Wh3) ; h update =====
        for (int ck = 12; ck < 20; ++ck) {
            const float* src = rhT + (ck-12)*(64*BB);
            __syncthreads();
            for (int i = tid; i < 4096; i += 256) {
                int dl = i >> 6, mm = i & 63;
                ldsA[dl*LDA + mm] = src[i];
            }
            __syncthreads();
            const int d0 = ck*64;
            if (!isZR) {
                #pragma unroll 8
                for (int dl = 0; dl < 64; ++dl) {
                    accB = fmaf(ldsA[dl*LDA + m], wh[d0+dl], accB);
                }
            }
        }
        if (!isZR) {
            float hh = tanhf(accA + bias[j3 + 2*HHH] + accB);
            float z  = zh[j3i][0][m];
            float ho = zh[j3i][1][m];
            float hn = z*ho + (1.f - z)*hh;
            h[m*HHH + j3]  = hn;
            hT[j3*BB + m]  = hn;
            out[((size_t)m*TDEC + t)*HHH + j3] = hn;
        }
        gbar(bar);
    }
}

extern "C" void kernel_launch(void* const* d_in, const int* in_sizes, int n_in,
                              void* d_out, int out_size, void* d_ws, size_t ws_size,
                              hipStream_t stream) {
    const float* inputs = (const float*)d_in[0];
    const float* C      = (const float*)d_in[1];
    const float* w1     = (const float*)d_in[2];
    const float* w2     = (const float*)d_in[3];
    const float* Wx     = (const float*)d_in[4];
    const float* Wh     = (const float*)d_in[5];
    const float* bias   = (const float*)d_in[6];
    float* out = (float*)d_out;
    float* ws  = (float*)d_ws;

    // reset barrier state every call (deterministic across replays)
    hipMemsetAsync(ws, 0, 256, stream);

    k_u   <<<1024, 64,  0, stream>>>(w1, w2, ws + OFF_U);
    k_ectx<<<(BB*TENC)/4, 256, 0, stream>>>(C, ws + OFF_U, ws + OFF_ECTX);
    decoder_main<<<256, 256, 0, stream>>>(inputs, C, Wx, Wh, bias, out, ws);
}